// Round 2
// baseline (239.157 us; speedup 1.0000x reference)
//
#include <hip/hip_runtime.h>

// Problem constants: B=8, N=2048, D=32, H=4, HD=8
// Layouts in workspace:
//   q_ws/k_ws/v_ws: [B*H][N][8]  (2MB each)
//   attn_ws:        [B*N][32]    (2MB)

__global__ __launch_bounds__(256) void qkv_kernel(
    const float* __restrict__ x, const float* __restrict__ Wqkv,
    const float* __restrict__ bqkv, float* __restrict__ q_ws,
    float* __restrict__ k_ws, float* __restrict__ v_ws) {
  __shared__ float Ws[32 * 96];
  __shared__ float bsh[96];
  __shared__ float xs[16 * 32];
  int tid = threadIdx.x;
  for (int i = tid; i < 32 * 96; i += 256) Ws[i] = Wqkv[i];
  if (tid < 96) bsh[tid] = bqkv[tid];
  int rowbase = blockIdx.x * 16;
  for (int i = tid; i < 16 * 32; i += 256) xs[i] = x[rowbase * 32 + i];
  __syncthreads();
#pragma unroll
  for (int e = 0; e < 6; ++e) {
    int idx = tid + e * 256;
    int r = idx / 96, c = idx % 96;
    float acc = bsh[c];
#pragma unroll
    for (int k = 0; k < 32; ++k) acc += xs[r * 32 + k] * Ws[k * 96 + c];
    int nrow = rowbase + r;
    int b = nrow >> 11, n = nrow & 2047;
    int s = c >> 5, h = (c >> 3) & 3, d = c & 7;
    float* dst = (s == 0) ? q_ws : (s == 1) ? k_ws : v_ws;
    dst[((((size_t)b * 4 + h) * 2048 + n) * 8) + d] = acc;
  }
}

__global__ __launch_bounds__(256) void attn_kernel(
    const float* __restrict__ q_ws, const float* __restrict__ k_ws,
    const float* __restrict__ v_ws, const float* __restrict__ adj,
    const float* __restrict__ gw_p, float* __restrict__ attn_ws) {
  int blk = blockIdx.x;
  int bh = blk & 31;       // (b,h) varies fastest -> concurrent blocks share adj rows
  int qgroup = blk >> 5;   // 128 qgroups, 16 queries each (N=2048)
  int wave = threadIdx.x >> 6;
  int lane = threadIdx.x & 63;
  int q0 = qgroup * 16 + wave * 4;  // this wave's 4 queries (0..2044)
  int b = bh >> 2, h = bh & 3;
  float gw = gw_p[0];
  float blend = 1.0f / (1.0f + __expf(-gw));
  float c1 = (1.0f - blend) * 0.35355339059327373f;  // (1-blend)/sqrt(8)
  float c2 = blend * 5.0f;

  const float* kb = k_ws + (size_t)bh * 2048 * 8;
  const float* vb = v_ws + (size_t)bh * 2048 * 8;
  const float* qb = q_ws + (size_t)bh * 2048 * 8;

  float qr[4][8];
#pragma unroll
  for (int qi = 0; qi < 4; ++qi) {
    float4 a = *(const float4*)(qb + (size_t)(q0 + qi) * 8);
    float4 bb = *(const float4*)(qb + (size_t)(q0 + qi) * 8 + 4);
    qr[qi][0] = a.x; qr[qi][1] = a.y; qr[qi][2] = a.z; qr[qi][3] = a.w;
    qr[qi][4] = bb.x; qr[qi][5] = bb.y; qr[qi][6] = bb.z; qr[qi][7] = bb.w;
  }
  float m[4], ss[4], o[4][8];
#pragma unroll
  for (int qi = 0; qi < 4; ++qi) {
    m[qi] = -1e30f; ss[qi] = 0.f;
#pragma unroll
    for (int d = 0; d < 8; ++d) o[qi][d] = 0.f;
  }

  for (int jb = 0; jb < 2048; jb += 64) {
    int j = jb + lane;
    float4 k1 = *(const float4*)(kb + (size_t)j * 8);
    float4 k2 = *(const float4*)(kb + (size_t)j * 8 + 4);
    float4 v1 = *(const float4*)(vb + (size_t)j * 8);
    float4 v2 = *(const float4*)(vb + (size_t)j * 8 + 4);
#pragma unroll
    for (int qi = 0; qi < 4; ++qi) {
      float dot = qr[qi][0] * k1.x + qr[qi][1] * k1.y + qr[qi][2] * k1.z + qr[qi][3] * k1.w
                + qr[qi][4] * k2.x + qr[qi][5] * k2.y + qr[qi][6] * k2.z + qr[qi][7] * k2.w;
      float s = c1 * dot + c2 * adj[(size_t)(q0 + qi) * 2048 + j];
      if (s > m[qi]) {  // rare after warm-up; per-lane masked
        float c = __expf(m[qi] - s);
        ss[qi] *= c;
#pragma unroll
        for (int d = 0; d < 8; ++d) o[qi][d] *= c;
        m[qi] = s;
      }
      float p = __expf(s - m[qi]);
      ss[qi] += p;
      o[qi][0] += p * v1.x; o[qi][1] += p * v1.y; o[qi][2] += p * v1.z; o[qi][3] += p * v1.w;
      o[qi][4] += p * v2.x; o[qi][5] += p * v2.y; o[qi][6] += p * v2.z; o[qi][7] += p * v2.w;
    }
  }

  // cross-lane online-softmax merge (butterfly over 64 lanes)
#pragma unroll
  for (int off = 32; off >= 1; off >>= 1) {
#pragma unroll
    for (int qi = 0; qi < 4; ++qi) {
      float m2 = __shfl_xor(m[qi], off);
      float s2 = __shfl_xor(ss[qi], off);
      float mn = fmaxf(m[qi], m2);
      float ca = __expf(m[qi] - mn), cb = __expf(m2 - mn);
      ss[qi] = ss[qi] * ca + s2 * cb;
#pragma unroll
      for (int d = 0; d < 8; ++d) {
        float o2 = __shfl_xor(o[qi][d], off);
        o[qi][d] = o[qi][d] * ca + o2 * cb;
      }
      m[qi] = mn;
    }
  }

  // lanes 0..31 each write one (query, dim) element; select via unrolled
  // compile-time compares (no runtime register indexing -> no scratch)
  if (lane < 32) {
    int qi = lane >> 3, d = lane & 7;
    float val = 0.f, den = 1.f;
#pragma unroll
    for (int a = 0; a < 4; ++a) {
      if (qi == a) {
        den = ss[a];
#pragma unroll
        for (int dd = 0; dd < 8; ++dd) {
          if (d == dd) val = o[a][dd];
        }
      }
    }
    int n = q0 + qi;
    attn_ws[(((size_t)b * 2048 + n) * 32) + h * 8 + d] = val / den;
  }
}

__global__ __launch_bounds__(256) void out_ln_kernel(
    const float* __restrict__ attn_ws, const float* __restrict__ x,
    const float* __restrict__ Wout, const float* __restrict__ bout,
    const float* __restrict__ gamma, const float* __restrict__ beta,
    float* __restrict__ out) {
  __shared__ float Ws[32 * 32];
  __shared__ float bs[32], gs[32], bts[32];
  int tid = threadIdx.x;
  for (int i = tid; i < 1024; i += 256) Ws[i] = Wout[i];
  if (tid < 32) { bs[tid] = bout[tid]; gs[tid] = gamma[tid]; bts[tid] = beta[tid]; }
  __syncthreads();
  int row = blockIdx.x * 8 + (tid >> 5);
  int d = tid & 31;
  const float* ar = attn_ws + (size_t)row * 32;
  float acc = bs[d];
#pragma unroll
  for (int k = 0; k < 32; ++k) acc += ar[k] * Ws[k * 32 + d];
  float res = acc + x[(size_t)row * 32 + d];
  float s1 = res, s2 = res * res;
#pragma unroll
  for (int off = 16; off >= 1; off >>= 1) {
    s1 += __shfl_xor(s1, off);
    s2 += __shfl_xor(s2, off);
  }
  float mu = s1 * 0.03125f;
  float var = s2 * 0.03125f - mu * mu;
  float r = rsqrtf(var + 1e-5f);
  out[(size_t)row * 32 + d] = (res - mu) * r * gs[d] + bts[d];
}

extern "C" void kernel_launch(void* const* d_in, const int* in_sizes, int n_in,
                              void* d_out, int out_size, void* d_ws, size_t ws_size,
                              hipStream_t stream) {
  const float* x     = (const float*)d_in[0];
  const float* adj   = (const float*)d_in[1];
  const float* gw    = (const float*)d_in[2];
  const float* Wqkv  = (const float*)d_in[3];
  const float* bqkv  = (const float*)d_in[4];
  const float* Wout  = (const float*)d_in[5];
  const float* bout  = (const float*)d_in[6];
  const float* gamma = (const float*)d_in[7];
  const float* beta  = (const float*)d_in[8];
  float* out = (float*)d_out;

  float* ws = (float*)d_ws;
  float* q_ws = ws;                    // 524288 floats
  float* k_ws = ws + 524288;           // 524288 floats
  float* v_ws = ws + 2 * 524288;       // 524288 floats
  float* attn_ws = ws + 3 * 524288;    // 524288 floats  (8MB total)

  qkv_kernel<<<1024, 256, 0, stream>>>(x, Wqkv, bqkv, q_ws, k_ws, v_ws);
  attn_kernel<<<4096, 256, 0, stream>>>(q_ws, k_ws, v_ws, adj, gw, attn_ws);
  out_ln_kernel<<<2048, 256, 0, stream>>>(attn_ws, x, Wout, bout, gamma, beta, out);
}

// Round 3
// 133.210 us; speedup vs baseline: 1.7953x; 1.7953x over previous
//
#include <hip/hip_runtime.h>

// Problem constants: B=8, N=2048, D=32, H=4, HD=8
// Layouts in workspace:
//   q_ws/k_ws/v_ws: [B*H][N][8]  (2MB each)
//   attn_ws:        [B*N][32]    (2MB)
//
// R3: fixed-max softmax (scores bounded |s|<~4 << 88 -> exp never overflows),
// log2e+c1 folded into q, exp2 via builtin, double-buffered K/V/adj loads.

__global__ __launch_bounds__(256) void qkv_kernel(
    const float* __restrict__ x, const float* __restrict__ Wqkv,
    const float* __restrict__ bqkv, float* __restrict__ q_ws,
    float* __restrict__ k_ws, float* __restrict__ v_ws) {
  __shared__ float Ws[32 * 96];
  __shared__ float bsh[96];
  __shared__ float xs[16 * 32];
  int tid = threadIdx.x;
  for (int i = tid; i < 32 * 96; i += 256) Ws[i] = Wqkv[i];
  if (tid < 96) bsh[tid] = bqkv[tid];
  int rowbase = blockIdx.x * 16;
  for (int i = tid; i < 16 * 32; i += 256) xs[i] = x[rowbase * 32 + i];
  __syncthreads();
#pragma unroll
  for (int e = 0; e < 6; ++e) {
    int idx = tid + e * 256;
    int r = idx / 96, c = idx % 96;
    float acc = bsh[c];
#pragma unroll
    for (int k = 0; k < 32; ++k) acc += xs[r * 32 + k] * Ws[k * 96 + c];
    int nrow = rowbase + r;
    int b = nrow >> 11, n = nrow & 2047;
    int s = c >> 5, h = (c >> 3) & 3, d = c & 7;
    float* dst = (s == 0) ? q_ws : (s == 1) ? k_ws : v_ws;
    dst[((((size_t)b * 4 + h) * 2048 + n) * 8) + d] = acc;
  }
}

// Load one 64-key tile (K,V as float4 pairs; one adj element per query row).
#define LOADT(SUF, JB)                                            \
  {                                                               \
    int j_ = (JB) + lane;                                         \
    const float* kp_ = kb + (size_t)j_ * 8;                       \
    const float* vp_ = vb + (size_t)j_ * 8;                       \
    k1##SUF = *(const float4*)kp_;                                \
    k2##SUF = *(const float4*)(kp_ + 4);                          \
    v1##SUF = *(const float4*)vp_;                                \
    v2##SUF = *(const float4*)(vp_ + 4);                          \
    _Pragma("unroll") for (int qi = 0; qi < 4; ++qi)              \
        a##SUF[qi] = adjq[qi][j_];                                \
  }

// Per-tile compute: t = c2'*adj + qr'.k ; p = 2^t ; accumulate.
#define COMPT(SUF)                                                \
  {                                                               \
    _Pragma("unroll") for (int qi = 0; qi < 4; ++qi) {            \
      float t = c2 * a##SUF[qi];                                  \
      t = fmaf(qr[qi][0], k1##SUF.x, t);                          \
      t = fmaf(qr[qi][1], k1##SUF.y, t);                          \
      t = fmaf(qr[qi][2], k1##SUF.z, t);                          \
      t = fmaf(qr[qi][3], k1##SUF.w, t);                          \
      t = fmaf(qr[qi][4], k2##SUF.x, t);                          \
      t = fmaf(qr[qi][5], k2##SUF.y, t);                          \
      t = fmaf(qr[qi][6], k2##SUF.z, t);                          \
      t = fmaf(qr[qi][7], k2##SUF.w, t);                          \
      float p = __builtin_amdgcn_exp2f(t);                        \
      ss[qi] += p;                                                \
      o[qi][0] = fmaf(p, v1##SUF.x, o[qi][0]);                    \
      o[qi][1] = fmaf(p, v1##SUF.y, o[qi][1]);                    \
      o[qi][2] = fmaf(p, v1##SUF.z, o[qi][2]);                    \
      o[qi][3] = fmaf(p, v1##SUF.w, o[qi][3]);                    \
      o[qi][4] = fmaf(p, v2##SUF.x, o[qi][4]);                    \
      o[qi][5] = fmaf(p, v2##SUF.y, o[qi][5]);                    \
      o[qi][6] = fmaf(p, v2##SUF.z, o[qi][6]);                    \
      o[qi][7] = fmaf(p, v2##SUF.w, o[qi][7]);                    \
    }                                                             \
  }

__global__ __launch_bounds__(256) void attn_kernel(
    const float* __restrict__ q_ws, const float* __restrict__ k_ws,
    const float* __restrict__ v_ws, const float* __restrict__ adj,
    const float* __restrict__ gw_p, float* __restrict__ attn_ws) {
  int blk = blockIdx.x;
  int bh = blk & 31;       // (b,h) fastest -> concurrent blocks share adj rows
  int qgroup = blk >> 5;   // 128 qgroups, 16 queries each
  int wave = threadIdx.x >> 6;
  int lane = threadIdx.x & 63;
  int q0 = qgroup * 16 + wave * 4;
  int b = bh >> 2, h = bh & 3;

  const float LOG2E = 1.4426950408889634f;
  float gw = gw_p[0];
  float blend = 1.0f / (1.0f + __expf(-gw));
  float c1 = (1.0f - blend) * 0.35355339059327373f * LOG2E;  // folded into q
  float c2 = blend * 5.0f * LOG2E;

  const float* kb = k_ws + (size_t)bh * 2048 * 8;
  const float* vb = v_ws + (size_t)bh * 2048 * 8;
  const float* qb = q_ws + (size_t)bh * 2048 * 8;
  const float* adjq[4];
#pragma unroll
  for (int qi = 0; qi < 4; ++qi) adjq[qi] = adj + (size_t)(q0 + qi) * 2048;

  float qr[4][8];
#pragma unroll
  for (int qi = 0; qi < 4; ++qi) {
    float4 a = *(const float4*)(qb + (size_t)(q0 + qi) * 8);
    float4 bb = *(const float4*)(qb + (size_t)(q0 + qi) * 8 + 4);
    qr[qi][0] = c1 * a.x;  qr[qi][1] = c1 * a.y;
    qr[qi][2] = c1 * a.z;  qr[qi][3] = c1 * a.w;
    qr[qi][4] = c1 * bb.x; qr[qi][5] = c1 * bb.y;
    qr[qi][6] = c1 * bb.z; qr[qi][7] = c1 * bb.w;
  }
  float ss[4], o[4][8];
#pragma unroll
  for (int qi = 0; qi < 4; ++qi) {
    ss[qi] = 0.f;
#pragma unroll
    for (int d = 0; d < 8; ++d) o[qi][d] = 0.f;
  }

  float4 k1A, k2A, v1A, v2A, k1B, k2B, v1B, v2B;
  float aA[4], aB[4];

  LOADT(A, 0);
  for (int jb = 0; jb < 2048; jb += 128) {
    LOADT(B, jb + 64);
    COMPT(A);
    if (jb + 128 < 2048) { LOADT(A, jb + 128); }
    COMPT(B);
  }

  // pure additive butterfly reduction over 64 lanes
#pragma unroll
  for (int off = 32; off >= 1; off >>= 1) {
#pragma unroll
    for (int qi = 0; qi < 4; ++qi) {
      ss[qi] += __shfl_xor(ss[qi], off);
#pragma unroll
      for (int d = 0; d < 8; ++d) o[qi][d] += __shfl_xor(o[qi][d], off);
    }
  }

  if (lane < 32) {
    int qi = lane >> 3, d = lane & 7;
    float val = 0.f, den = 1.f;
#pragma unroll
    for (int a = 0; a < 4; ++a) {
      if (qi == a) {
        den = ss[a];
#pragma unroll
        for (int dd = 0; dd < 8; ++dd) {
          if (d == dd) val = o[a][dd];
        }
      }
    }
    int n = q0 + qi;
    attn_ws[(((size_t)b * 2048 + n) * 32) + h * 8 + d] = val / den;
  }
}

__global__ __launch_bounds__(256) void out_ln_kernel(
    const float* __restrict__ attn_ws, const float* __restrict__ x,
    const float* __restrict__ Wout, const float* __restrict__ bout,
    const float* __restrict__ gamma, const float* __restrict__ beta,
    float* __restrict__ out) {
  __shared__ float Ws[32 * 32];
  __shared__ float bs[32], gs[32], bts[32];
  int tid = threadIdx.x;
  for (int i = tid; i < 1024; i += 256) Ws[i] = Wout[i];
  if (tid < 32) { bs[tid] = bout[tid]; gs[tid] = gamma[tid]; bts[tid] = beta[tid]; }
  __syncthreads();
  int row = blockIdx.x * 8 + (tid >> 5);
  int d = tid & 31;
  const float* ar = attn_ws + (size_t)row * 32;
  float acc = bs[d];
#pragma unroll
  for (int k = 0; k < 32; ++k) acc += ar[k] * Ws[k * 32 + d];
  float res = acc + x[(size_t)row * 32 + d];
  float s1 = res, s2 = res * res;
#pragma unroll
  for (int off = 16; off >= 1; off >>= 1) {
    s1 += __shfl_xor(s1, off);
    s2 += __shfl_xor(s2, off);
  }
  float mu = s1 * 0.03125f;
  float var = s2 * 0.03125f - mu * mu;
  float r = rsqrtf(var + 1e-5f);
  out[(size_t)row * 32 + d] = (res - mu) * r * gs[d] + bts[d];
}

extern "C" void kernel_launch(void* const* d_in, const int* in_sizes, int n_in,
                              void* d_out, int out_size, void* d_ws, size_t ws_size,
                              hipStream_t stream) {
  const float* x     = (const float*)d_in[0];
  const float* adj   = (const float*)d_in[1];
  const float* gw    = (const float*)d_in[2];
  const float* Wqkv  = (const float*)d_in[3];
  const float* bqkv  = (const float*)d_in[4];
  const float* Wout  = (const float*)d_in[5];
  const float* bout  = (const float*)d_in[6];
  const float* gamma = (const float*)d_in[7];
  const float* beta  = (const float*)d_in[8];
  float* out = (float*)d_out;

  float* ws = (float*)d_ws;
  float* q_ws = ws;                    // 524288 floats
  float* k_ws = ws + 524288;           // 524288 floats
  float* v_ws = ws + 2 * 524288;       // 524288 floats
  float* attn_ws = ws + 3 * 524288;    // 524288 floats  (8MB total)

  qkv_kernel<<<1024, 256, 0, stream>>>(x, Wqkv, bqkv, q_ws, k_ws, v_ws);
  attn_kernel<<<4096, 256, 0, stream>>>(q_ws, k_ws, v_ws, adj, gw, attn_ws);
  out_ln_kernel<<<2048, 256, 0, stream>>>(attn_ws, x, Wout, bout, gamma, beta, out);
}